// Round 1
// 306.926 us; speedup vs baseline: 1.2348x; 1.2348x over previous
//
#include <hip/hip_runtime.h>

#define KVSZ 288            // per-cloud: 256 kv[h][d][e] + 32 ksum[feat]
#define EPS_LN 1e-5f
#define EPS_Z  1e-6f

typedef __attribute__((ext_vector_type(8))) short bf16x8;   // MFMA A/B frag (4 VGPR)
typedef __attribute__((ext_vector_type(4))) float f32x4;    // MFMA C/D frag

#define MFMA(a, b, c) __builtin_amdgcn_mfma_f32_16x16x32_bf16(a, b, c, 0, 0, 0)

// staged-weight element offsets (k_mid / k_last layout)
#define WQ  0
#define WO  1024
#define KVM 2048
#define W1  3072
#define W2  5120
#define WKN 7168
#define WVN 8192

__device__ __forceinline__ unsigned short f2bf(float f) {   // fp32 -> bf16 RNE
  union { float f; unsigned u; } x; x.f = f;
  unsigned r = x.u + 0x7fff + ((x.u >> 16) & 1);
  return (unsigned short)(r >> 16);
}

__device__ __forceinline__ unsigned pkbf(float a, float b) {
#if __has_builtin(__builtin_amdgcn_cvt_pk_bf16_f32)
  typedef __attribute__((ext_vector_type(2))) __bf16 bf16x2_t;
  bf16x2_t v = __builtin_amdgcn_cvt_pk_bf16_f32(a, b);
  return __builtin_bit_cast(unsigned, v);
#else
  return (unsigned)f2bf(a) | ((unsigned)f2bf(b) << 16);
#endif
}

__device__ __forceinline__ void lds_fence() { asm volatile("s_waitcnt lgkmcnt(0)" ::: "memory"); }
__device__ __forceinline__ float phi(float x) { return x > 0.f ? x + 1.f : __expf(x); }

// Feature-major dataflow: D'[out_feat][point] = W^T (A-frag) @ h^T (B-frag).
// B-frag k-order: lane-group q, slot j -> feature (j>=4)*16 + 4q + (j&3).
// This makes D-frag regs {hc0[r]=feat 4q+r, hc1[r]=feat 16+4q+r} directly
// packable (in-lane cvt_pk) into the next B operand: NO LDS transposes.
__device__ __forceinline__ int perm32(int kp) {
  return ((kp & 4) << 2) | (((kp >> 3) << 2) + (kp & 3));
}

// build B operand from two D frags (lo: feats {4q..4q+3}, hi: {16+4q..16+4q+3})
__device__ __forceinline__ bf16x8 bbuild(f32x4 lo, f32x4 hi) {
  union { bf16x8 v; unsigned u[4]; } cv;
  cv.u[0] = pkbf(lo[0], lo[1]); cv.u[1] = pkbf(lo[2], lo[3]);
  cv.u[2] = pkbf(hi[0], hi[1]); cv.u[3] = pkbf(hi[2], hi[3]);
  return cv.v;
}

// ---- cooperative weight staging: dst[n*32+kp] = W[perm32(kp)][n] ----
__device__ __forceinline__ void stage_a32(unsigned short* dst, const float* __restrict__ W,
                                          int N, int tid) {
  for (int i = tid; i < 32 * N; i += 256) {
    int n = i >> 5, kp = i & 31;
    dst[i] = f2bf(W[perm32(kp) * N + n]);
  }
}
// w2: [64][32], K=64 packed in two 32-halves: dst[n*64+kp]
__device__ __forceinline__ void stage_a64(unsigned short* dst, const float* __restrict__ W,
                                          int tid) {
  for (int i = tid; i < 64 * 32; i += 256) {
    int n = i >> 6, kp = i & 63;
    int kl = ((kp >> 5) << 5) + perm32(kp & 31);
    dst[i] = f2bf(W[kl * 32 + n]);
  }
}
// block-diagonal kv summary: A[e][d] = same-head ? kv[h][d][e] : 0 (d = perm32(kp))
__device__ __forceinline__ void stage_kvm_t(unsigned short* dst, const float* __restrict__ kvg,
                                            int tid) {
  for (int i = tid; i < 1024; i += 256) {
    int e = i >> 5, kp = i & 31;
    int d = perm32(kp);
    float v = ((d >> 3) == (e >> 3)) ? kvg[(e >> 3) * 64 + (d & 7) * 8 + (e & 7)] : 0.f;
    dst[i] = f2bf(v);
  }
}

// LayerNorm over 32 features, feature-major: in-lane over 8 regs + xor16/xor32.
__device__ __forceinline__ void ln_t(f32x4& a0, f32x4& a1, float4 g0, float4 g1,
                                     float4 b0, float4 b1) {
  float s = a0[0] + a0[1] + a0[2] + a0[3] + a1[0] + a1[1] + a1[2] + a1[3];
  s += __shfl_xor(s, 16); s += __shfl_xor(s, 32);
  float mu = s * (1.f / 32.f);
  float vv = 0.f;
#pragma unroll
  for (int r = 0; r < 4; r++) {
    a0[r] -= mu; a1[r] -= mu;
    vv += a0[r] * a0[r] + a1[r] * a1[r];
  }
  vv += __shfl_xor(vv, 16); vv += __shfl_xor(vv, 32);
  float rstd = rsqrtf(vv * (1.f / 32.f) + EPS_LN);
  a0[0] = a0[0] * rstd * g0.x + b0.x; a0[1] = a0[1] * rstd * g0.y + b0.y;
  a0[2] = a0[2] * rstd * g0.z + b0.z; a0[3] = a0[3] * rstd * g0.w + b0.w;
  a1[0] = a1[0] * rstd * g1.x + b1.x; a1[1] = a1[1] * rstd * g1.y + b1.y;
  a1[2] = a1[2] * rstd * g1.z + b1.z; a1[3] = a1[3] * rstd * g1.w + b1.w;
}

// attention + FFN for one layer, fully in-register (no LDS, no fences).
// Phase-split (attn | FFN) to bound register pressure.
__device__ __forceinline__ void layer_core_t(
    f32x4* hc0, f32x4* hc1, const unsigned short* ws, int quad, int m,
    const float* __restrict__ bq, const float* __restrict__ bo,
    const float* __restrict__ g1, const float* __restrict__ be1,
    const float* __restrict__ bf1, const float* __restrict__ bf2,
    const float* __restrict__ g2, const float* __restrict__ be2,
    const float* __restrict__ kvg) {
  const int k0 = quad * 8, q4 = quad * 4;
  // ---- phase A: q = phi(h@wq+bq); attn = (q@kvmat)*z; h = LN1(h + attn@wo+bo)
  {
    const bf16x8 wqA0 = *(const bf16x8*)(ws + WQ + m * 32 + k0);
    const bf16x8 wqA1 = *(const bf16x8*)(ws + WQ + (16 + m) * 32 + k0);
    const bf16x8 kvA0 = *(const bf16x8*)(ws + KVM + m * 32 + k0);
    const bf16x8 kvA1 = *(const bf16x8*)(ws + KVM + (16 + m) * 32 + k0);
    const bf16x8 woA0 = *(const bf16x8*)(ws + WO + m * 32 + k0);
    const bf16x8 woA1 = *(const bf16x8*)(ws + WO + (16 + m) * 32 + k0);
    const float4 bq0 = *(const float4*)(bq + q4), bq1 = *(const float4*)(bq + 16 + q4);
    const float4 bo0 = *(const float4*)(bo + q4), bo1 = *(const float4*)(bo + 16 + q4);
    const float4 g10 = *(const float4*)(g1 + q4), g11 = *(const float4*)(g1 + 16 + q4);
    const float4 e10 = *(const float4*)(be1 + q4), e11 = *(const float4*)(be1 + 16 + q4);
    const float4 ks0 = *(const float4*)(kvg + 256 + q4);
    const float4 ks1 = *(const float4*)(kvg + 272 + q4);
#pragma unroll
    for (int mt = 0; mt < 4; mt++) {
      bf16x8 hB = bbuild(hc0[mt], hc1[mt]);
      f32x4 q0 = {bq0.x, bq0.y, bq0.z, bq0.w};
      f32x4 q1 = {bq1.x, bq1.y, bq1.z, bq1.w};
      q0 = MFMA(wqA0, hB, q0);
      q1 = MFMA(wqA1, hB, q1);
#pragma unroll
      for (int r = 0; r < 4; r++) { q0[r] = phi(q0[r]); q1[r] = phi(q1[r]); }
      bf16x8 qB = bbuild(q0, q1);
      f32x4 zz = {0.f, 0.f, 0.f, 0.f};
      f32x4 at0 = MFMA(kvA0, qB, zz);
      f32x4 at1 = MFMA(kvA1, qB, zz);
      // z: per-head (8-feat) q.ksum; groups q and q^1 hold the two 4-feat halves
      float p0 = q0[0] * ks0.x + q0[1] * ks0.y + q0[2] * ks0.z + q0[3] * ks0.w;
      float p1 = q1[0] * ks1.x + q1[1] * ks1.y + q1[2] * ks1.z + q1[3] * ks1.w;
      p0 += __shfl_xor(p0, 16);
      p1 += __shfl_xor(p1, 16);
      float z0 = 1.f / (p0 + EPS_Z), z1 = 1.f / (p1 + EPS_Z);
      bf16x8 aB;
      {
        union { bf16x8 v; unsigned u[4]; } cv;
        cv.u[0] = pkbf(at0[0] * z0, at0[1] * z0); cv.u[1] = pkbf(at0[2] * z0, at0[3] * z0);
        cv.u[2] = pkbf(at1[0] * z1, at1[1] * z1); cv.u[3] = pkbf(at1[2] * z1, at1[3] * z1);
        aB = cv.v;
      }
      f32x4 h0 = hc0[mt], h1 = hc1[mt];
      h0[0] += bo0.x; h0[1] += bo0.y; h0[2] += bo0.z; h0[3] += bo0.w;
      h1[0] += bo1.x; h1[1] += bo1.y; h1[2] += bo1.z; h1[3] += bo1.w;
      h0 = MFMA(woA0, aB, h0);
      h1 = MFMA(woA1, aB, h1);
      ln_t(h0, h1, g10, g11, e10, e11);
      hc0[mt] = h0; hc1[mt] = h1;
    }
  }
  // ---- phase B: h = LN2(h + relu(h@w1+b1)@w2+b2)
  {
    bf16x8 w1A[4]; float4 b1f[4];
#pragma unroll
    for (int nt = 0; nt < 4; nt++) {
      w1A[nt] = *(const bf16x8*)(ws + W1 + (nt * 16 + m) * 32 + k0);
      b1f[nt] = *(const float4*)(bf1 + nt * 16 + q4);
    }
    const bf16x8 w2L0 = *(const bf16x8*)(ws + W2 + m * 64 + k0);
    const bf16x8 w2H0 = *(const bf16x8*)(ws + W2 + m * 64 + 32 + k0);
    const bf16x8 w2L1 = *(const bf16x8*)(ws + W2 + (16 + m) * 64 + k0);
    const bf16x8 w2H1 = *(const bf16x8*)(ws + W2 + (16 + m) * 64 + 32 + k0);
    const float4 b20 = *(const float4*)(bf2 + q4), b21 = *(const float4*)(bf2 + 16 + q4);
    const float4 g20 = *(const float4*)(g2 + q4), g21 = *(const float4*)(g2 + 16 + q4);
    const float4 e20 = *(const float4*)(be2 + q4), e21 = *(const float4*)(be2 + 16 + q4);
#pragma unroll
    for (int mt = 0; mt < 4; mt++) {
      bf16x8 hB = bbuild(hc0[mt], hc1[mt]);
      f32x4 hd[4];
#pragma unroll
      for (int nt = 0; nt < 4; nt++) {
        f32x4 ini = {b1f[nt].x, b1f[nt].y, b1f[nt].z, b1f[nt].w};
        hd[nt] = MFMA(w1A[nt], hB, ini);
#pragma unroll
        for (int r = 0; r < 4; r++) hd[nt][r] = fmaxf(hd[nt][r], 0.f);
      }
      bf16x8 fL = bbuild(hd[0], hd[1]);
      bf16x8 fH = bbuild(hd[2], hd[3]);
      f32x4 o0 = hc0[mt], o1 = hc1[mt];
      o0[0] += b20.x; o0[1] += b20.y; o0[2] += b20.z; o0[3] += b20.w;
      o1[0] += b21.x; o1[1] += b21.y; o1[2] += b21.z; o1[3] += b21.w;
      o0 = MFMA(w2L0, fL, o0);
      o0 = MFMA(w2H0, fH, o0);
      o1 = MFMA(w2L1, fL, o1);
      o1 = MFMA(w2H1, fH, o1);
      ln_t(o0, o1, g20, g21, e20, e21);
      hc0[mt] = o0; hc1[mt] = o1;
    }
  }
}

// kn = phi(h@wk+bk), vn = h@wv+bv (feature-major in regs); kv += kn^T-outer-vn
// via ONE LDS transpose per 32-point chunk (points are the contraction dim).
__device__ __forceinline__ void kv_stage_t(
    const f32x4* hc0, const f32x4* hc1, unsigned short* tw, const unsigned short* ws,
    int offk, int offv, float* blk, int quad, int m,
    const float* __restrict__ bk, const float* __restrict__ bv) {
  const int k0 = quad * 8, q4 = quad * 4;
  unsigned short* Tk = tw;           // [32 feat][40] bf16
  unsigned short* Tv = tw + 1280;    // [32 feat][40] bf16
  const bf16x8 wkA0 = *(const bf16x8*)(ws + offk + m * 32 + k0);
  const bf16x8 wkA1 = *(const bf16x8*)(ws + offk + (16 + m) * 32 + k0);
  const bf16x8 wvA0 = *(const bf16x8*)(ws + offv + m * 32 + k0);
  const bf16x8 wvA1 = *(const bf16x8*)(ws + offv + (16 + m) * 32 + k0);
  const float4 bk0 = *(const float4*)(bk + q4), bk1 = *(const float4*)(bk + 16 + q4);
  const float4 bv0 = *(const float4*)(bv + q4), bv1 = *(const float4*)(bv + 16 + q4);
  f32x4 accA = {0.f, 0.f, 0.f, 0.f}, accB = {0.f, 0.f, 0.f, 0.f};
  f32x4 ksa0 = {0.f, 0.f, 0.f, 0.f}, ksa1 = {0.f, 0.f, 0.f, 0.f};
#pragma unroll
  for (int ch = 0; ch < 2; ch++) {
#pragma unroll
    for (int mtl = 0; mtl < 2; mtl++) {
      int mt = ch * 2 + mtl;
      bf16x8 hB = bbuild(hc0[mt], hc1[mt]);
      f32x4 kn0 = {bk0.x, bk0.y, bk0.z, bk0.w};
      f32x4 kn1 = {bk1.x, bk1.y, bk1.z, bk1.w};
      f32x4 vn0 = {bv0.x, bv0.y, bv0.z, bv0.w};
      f32x4 vn1 = {bv1.x, bv1.y, bv1.z, bv1.w};
      kn0 = MFMA(wkA0, hB, kn0);
      kn1 = MFMA(wkA1, hB, kn1);
      vn0 = MFMA(wvA0, hB, vn0);
      vn1 = MFMA(wvA1, hB, vn1);
      int cb = mtl * 16 + m;
#pragma unroll
      for (int r = 0; r < 4; r++) {
        kn0[r] = phi(kn0[r]); kn1[r] = phi(kn1[r]);
        ksa0[r] += kn0[r];    ksa1[r] += kn1[r];
        Tk[(q4 + r) * 40 + cb]      = f2bf(kn0[r]);
        Tk[(16 + q4 + r) * 40 + cb] = f2bf(kn1[r]);
        Tv[(q4 + r) * 40 + cb]      = f2bf(vn0[r]);
        Tv[(16 + q4 + r) * 40 + cb] = f2bf(vn1[r]);
      }
    }
    lds_fence();
    bf16x8 akL = *(const bf16x8*)(Tk + m * 40 + k0);
    bf16x8 akH = *(const bf16x8*)(Tk + (16 + m) * 40 + k0);
    bf16x8 avL = *(const bf16x8*)(Tv + m * 40 + k0);
    bf16x8 avH = *(const bf16x8*)(Tv + (16 + m) * 40 + k0);
    accA = MFMA(akL, avL, accA);   // d,e in 0..15  (heads 0,1 diag blocks)
    accB = MFMA(akH, avH, accB);   // d,e in 16..31 (heads 2,3 diag blocks)
    lds_fence();
  }
  // ksum[feat]: reduce over the 16 point-lanes
#pragma unroll
  for (int r = 0; r < 4; r++) {
    float v0 = ksa0[r], v1 = ksa1[r];
    v0 += __shfl_xor(v0, 1); v0 += __shfl_xor(v0, 2); v0 += __shfl_xor(v0, 4); v0 += __shfl_xor(v0, 8);
    v1 += __shfl_xor(v1, 1); v1 += __shfl_xor(v1, 2); v1 += __shfl_xor(v1, 4); v1 += __shfl_xor(v1, 8);
    if (m == 0) {
      atomicAdd(&blk[256 + q4 + r], v0);
      atomicAdd(&blk[272 + q4 + r], v1);
    }
  }
  if ((quad >> 1) == (m >> 3)) {   // same-head diagonal blocks only
    int h0 = quad >> 1, h1 = 2 + (quad >> 1), e = m & 7;
#pragma unroll
    for (int r = 0; r < 4; r++) {
      int d = (q4 + r) & 7;
      atomicAdd(&blk[h0 * 64 + d * 8 + e], accA[r]);
      atomicAdd(&blk[h1 * 64 + d * 8 + e], accB[r]);
    }
  }
}

// K1: embed -> h0 (feature-major frags, fp32 to d_out), layer-0 kn/vn -> kv accum
__global__ __launch_bounds__(256) void k_embed(
    const float* __restrict__ x, const float* __restrict__ pos,
    const float* __restrict__ w_in, const float* __restrict__ b_in,
    const float* __restrict__ w_pos, const float* __restrict__ b_pos,
    const float* __restrict__ wk, const float* __restrict__ bk,
    const float* __restrict__ wv, const float* __restrict__ bv,
    float* __restrict__ hout, float* __restrict__ gkv) {
  __shared__ __align__(16) unsigned short ws[3072];
  __shared__ __align__(16) unsigned short tiles[4 * 2560];
  __shared__ float blk[KVSZ];
  const int tid = threadIdx.x;
  const int wv_ = tid >> 6, lane = tid & 63, quad = lane >> 4, m = lane & 15;
  unsigned short* tw = tiles + wv_ * 2560;
  for (int i = tid; i < 1024; i += 256) {           // wE: identity k-order (cin | pos | 0)
    int n = i >> 5, k = i & 31;
    float v = k < 16 ? w_in[k * 32 + n] : (k < 19 ? w_pos[(k - 16) * 32 + n] : 0.f);
    ws[i] = f2bf(v);
  }
  stage_a32(ws + 1024, wk, 32, tid);
  stage_a32(ws + 2048, wv, 32, tid);
  for (int i = tid; i < KVSZ; i += 256) blk[i] = 0.f;
  __syncthreads();
  const int wbase = blockIdx.x * 256 + wv_ * 64;
  const int cloud = blockIdx.x >> 7;
  const int k0 = quad * 8, q4 = quad * 4;
  const bf16x8 weA0 = *(const bf16x8*)(ws + m * 32 + k0);
  const bf16x8 weA1 = *(const bf16x8*)(ws + (16 + m) * 32 + k0);
  float4 bi0, bi1;
  {
    float4 a = *(const float4*)(b_in + q4), b = *(const float4*)(b_pos + q4);
    bi0 = make_float4(a.x + b.x, a.y + b.y, a.z + b.z, a.w + b.w);
    float4 c = *(const float4*)(b_in + 16 + q4), d = *(const float4*)(b_pos + 16 + q4);
    bi1 = make_float4(c.x + d.x, c.y + d.y, c.z + d.z, c.w + d.w);
  }
  f32x4 hc0[4], hc1[4];
#pragma unroll
  for (int mt = 0; mt < 4; mt++) {
    int p = wbase + mt * 16 + m;
    union { bf16x8 v; unsigned u[4]; } xb;
    xb.u[0] = xb.u[1] = xb.u[2] = xb.u[3] = 0;
    if (quad < 2) {
      const float4* xp = (const float4*)(x + (size_t)p * 16 + quad * 8);
      float4 t0 = xp[0], t1 = xp[1];
      xb.u[0] = pkbf(t0.x, t0.y); xb.u[1] = pkbf(t0.z, t0.w);
      xb.u[2] = pkbf(t1.x, t1.y); xb.u[3] = pkbf(t1.z, t1.w);
    } else if (quad == 2) {
      const float* pp = pos + (size_t)p * 3;
      xb.u[0] = pkbf(pp[0], pp[1]); xb.u[1] = pkbf(pp[2], 0.f);
    }
    f32x4 i0 = {bi0.x, bi0.y, bi0.z, bi0.w};
    f32x4 i1 = {bi1.x, bi1.y, bi1.z, bi1.w};
    hc0[mt] = MFMA(weA0, xb.v, i0);
    hc1[mt] = MFMA(weA1, xb.v, i1);
    float* hp = hout + (size_t)p * 32;
    *(float4*)(hp + q4)      = make_float4(hc0[mt][0], hc0[mt][1], hc0[mt][2], hc0[mt][3]);
    *(float4*)(hp + 16 + q4) = make_float4(hc1[mt][0], hc1[mt][1], hc1[mt][2], hc1[mt][3]);
  }
  kv_stage_t(hc0, hc1, tw, ws, 1024, 2048, blk, quad, m, bk, bv);
  __syncthreads();
  float* g = gkv + cloud * KVSZ;
  for (int i = tid; i < KVSZ; i += 256) atomicAdd(&g[i], blk[i]);
}

// K2: layer-0 attn+FFN (in place on hbuf), layer-1 kn/vn -> kv accum
__global__ __launch_bounds__(256) void k_mid(
    const float* __restrict__ wq, const float* __restrict__ bq,
    const float* __restrict__ wo, const float* __restrict__ bo,
    const float* __restrict__ g1, const float* __restrict__ be1,
    const float* __restrict__ w1, const float* __restrict__ bf1,
    const float* __restrict__ w2, const float* __restrict__ bf2,
    const float* __restrict__ g2, const float* __restrict__ be2,
    const float* __restrict__ wkn, const float* __restrict__ bkn,
    const float* __restrict__ wvn, const float* __restrict__ bvn,
    const float* __restrict__ kv_in, float* __restrict__ gkv_out,
    float* __restrict__ hbuf) {
  __shared__ __align__(16) unsigned short ws[9216];
  __shared__ __align__(16) unsigned short tiles[4 * 2560];
  __shared__ float blk[KVSZ];
  const int tid = threadIdx.x;
  const int wv_ = tid >> 6, lane = tid & 63, quad = lane >> 4, m = lane & 15;
  unsigned short* tw = tiles + wv_ * 2560;
  const int cloud = blockIdx.x >> 7;
  stage_a32(ws + WQ, wq, 32, tid);
  stage_a32(ws + WO, wo, 32, tid);
  stage_kvm_t(ws + KVM, kv_in + cloud * KVSZ, tid);
  stage_a32(ws + W1, w1, 64, tid);
  stage_a64(ws + W2, w2, tid);
  stage_a32(ws + WKN, wkn, 32, tid);
  stage_a32(ws + WVN, wvn, 32, tid);
  for (int i = tid; i < KVSZ; i += 256) blk[i] = 0.f;
  __syncthreads();
  const int wbase = blockIdx.x * 256 + wv_ * 64;
  const int q4 = quad * 4;
  f32x4 hc0[4], hc1[4];
#pragma unroll
  for (int mt = 0; mt < 4; mt++) {
    const float* hp = hbuf + (size_t)(wbase + mt * 16 + m) * 32;
    float4 lo = *(const float4*)(hp + q4);
    float4 hi = *(const float4*)(hp + 16 + q4);
    hc0[mt][0] = lo.x; hc0[mt][1] = lo.y; hc0[mt][2] = lo.z; hc0[mt][3] = lo.w;
    hc1[mt][0] = hi.x; hc1[mt][1] = hi.y; hc1[mt][2] = hi.z; hc1[mt][3] = hi.w;
  }
  layer_core_t(hc0, hc1, ws, quad, m, bq, bo, g1, be1, bf1, bf2, g2, be2,
               kv_in + cloud * KVSZ);
#pragma unroll
  for (int mt = 0; mt < 4; mt++) {
    float* hp = hbuf + (size_t)(wbase + mt * 16 + m) * 32;
    *(float4*)(hp + q4)      = make_float4(hc0[mt][0], hc0[mt][1], hc0[mt][2], hc0[mt][3]);
    *(float4*)(hp + 16 + q4) = make_float4(hc1[mt][0], hc1[mt][1], hc1[mt][2], hc1[mt][3]);
  }
  kv_stage_t(hc0, hc1, tw, ws, WKN, WVN, blk, quad, m, bkn, bvn);
  __syncthreads();
  float* g = gkv_out + cloud * KVSZ;
  for (int i = tid; i < KVSZ; i += 256) atomicAdd(&g[i], blk[i]);
}

// K3: layer-1 attn+FFN -> final output (in place on hbuf == d_out)
__global__ __launch_bounds__(256) void k_last(
    const float* __restrict__ wq, const float* __restrict__ bq,
    const float* __restrict__ wo, const float* __restrict__ bo,
    const float* __restrict__ g1, const float* __restrict__ be1,
    const float* __restrict__ w1, const float* __restrict__ bf1,
    const float* __restrict__ w2, const float* __restrict__ bf2,
    const float* __restrict__ g2, const float* __restrict__ be2,
    const float* __restrict__ kv_in, float* __restrict__ hbuf) {
  __shared__ __align__(16) unsigned short ws[7168];
  const int tid = threadIdx.x;
  const int wv_ = tid >> 6, lane = tid & 63, quad = lane >> 4, m = lane & 15;
  const int cloud = blockIdx.x >> 7;
  stage_a32(ws + WQ, wq, 32, tid);
  stage_a32(ws + WO, wo, 32, tid);
  stage_kvm_t(ws + KVM, kv_in + cloud * KVSZ, tid);
  stage_a32(ws + W1, w1, 64, tid);
  stage_a64(ws + W2, w2, tid);
  __syncthreads();
  const int wbase = blockIdx.x * 256 + wv_ * 64;
  const int q4 = quad * 4;
  f32x4 hc0[4], hc1[4];
#pragma unroll
  for (int mt = 0; mt < 4; mt++) {
    const float* hp = hbuf + (size_t)(wbase + mt * 16 + m) * 32;
    float4 lo = *(const float4*)(hp + q4);
    float4 hi = *(const float4*)(hp + 16 + q4);
    hc0[mt][0] = lo.x; hc0[mt][1] = lo.y; hc0[mt][2] = lo.z; hc0[mt][3] = lo.w;
    hc1[mt][0] = hi.x; hc1[mt][1] = hi.y; hc1[mt][2] = hi.z; hc1[mt][3] = hi.w;
  }
  layer_core_t(hc0, hc1, ws, quad, m, bq, bo, g1, be1, bf1, bf2, g2, be2,
               kv_in + cloud * KVSZ);
#pragma unroll
  for (int mt = 0; mt < 4; mt++) {
    float* hp = hbuf + (size_t)(wbase + mt * 16 + m) * 32;
    *(float4*)(hp + q4)      = make_float4(hc0[mt][0], hc0[mt][1], hc0[mt][2], hc0[mt][3]);
    *(float4*)(hp + 16 + q4) = make_float4(hc1[mt][0], hc1[mt][1], hc1[mt][2], hc1[mt][3]);
  }
}

extern "C" void kernel_launch(void* const* d_in, const int* in_sizes, int n_in,
                              void* d_out, int out_size, void* d_ws, size_t ws_size,
                              hipStream_t stream) {
  (void)in_sizes; (void)n_in; (void)out_size; (void)ws_size;
  const float* x     = (const float*)d_in[0];
  const float* pos   = (const float*)d_in[1];
  // d_in[2] = batch (arange // N_PER): identity mapping, unused
  const float* w_in  = (const float*)d_in[3];
  const float* b_in  = (const float*)d_in[4];
  const float* w_pos = (const float*)d_in[5];
  const float* b_pos = (const float*)d_in[6];
  const float* wq  = (const float*)d_in[7];
  const float* bq  = (const float*)d_in[8];
  const float* wk  = (const float*)d_in[9];
  const float* bk  = (const float*)d_in[10];
  const float* wv  = (const float*)d_in[11];
  const float* bv  = (const float*)d_in[12];
  const float* wo  = (const float*)d_in[13];
  const float* bo  = (const float*)d_in[14];
  const float* g1  = (const float*)d_in[15];
  const float* be1 = (const float*)d_in[16];
  const float* w1  = (const float*)d_in[17];
  const float* bf1 = (const float*)d_in[18];
  const float* w2  = (const float*)d_in[19];
  const float* bf2 = (const float*)d_in[20];
  const float* g2  = (const float*)d_in[21];
  const float* be2 = (const float*)d_in[22];
  float* out   = (float*)d_out;
  float* kvbuf = (float*)d_ws;   // 2 layers * 16 clouds * 288 floats

  hipMemsetAsync(kvbuf, 0, 2 * 16 * KVSZ * sizeof(float), stream);
  dim3 grid(2048), block(256);
  k_embed<<<grid, block, 0, stream>>>(x, pos, w_in, b_in, w_pos, b_pos,
                                      wk, bk, wv, bv, out, kvbuf);
  k_mid<<<grid, block, 0, stream>>>(wq, bq, wo, bo, g1, be1, w1, bf1, w2, bf2, g2, be2,
                                    wk + 1024, bk + 32, wv + 1024, bv + 32,
                                    kvbuf, kvbuf + 16 * KVSZ, out);
  k_last<<<grid, block, 0, stream>>>(wq + 1024, bq + 32, wo + 1024, bo + 32,
                                     g1 + 32, be1 + 32, w1 + 2048, bf1 + 64,
                                     w2 + 2048, bf2 + 32, g2 + 32, be2 + 32,
                                     kvbuf + 16 * KVSZ, out);
}